// Round 10
// baseline (87.411 us; speedup 1.0000x reference)
//
#include <hip/hip_runtime.h>

#define S_CONST 8
#define EPSF 1e-8f
#define WPB 4

struct Samp { int y; int a1[S_CONST]; int a2[S_CONST]; };

__device__ __forceinline__ void load_samp(Samp& sm, const int* __restrict__ Y,
                                          const int* __restrict__ s1g,
                                          const int* __restrict__ s2g,
                                          int B, int row, bool inb) {
    if (inb) {
        sm.y = Y[row];
        #pragma unroll
        for (int s = 0; s < S_CONST; ++s) {
            sm.a1[s] = s1g[(size_t)s * B + row];
            sm.a2[s] = s2g[(size_t)s * B + row];
        }
    } else {
        sm.y = -1;
        #pragma unroll
        for (int s = 0; s < S_CONST; ++s) { sm.a1[s] = 0; sm.a2[s] = 0; }
    }
}

// partials[nblocks]: float4 {ent, uniq, corr, rloo}
__global__ __launch_bounds__(256, 8) void fml_reduce(
        const float* __restrict__ pCS,
        const int* __restrict__ Y,
        const int* __restrict__ s1g,
        const int* __restrict__ s2g,
        float4* __restrict__ partials,
        int B)
{
    // EXACTLY 20480 B -> 8 blocks/CU (160KB/CU), one dispatch generation.
    // Final reduce reuses pan[0] after panels are dead (validated r9).
    __shared__ float pan[WPB][64 * 20];

    const int lane = threadIdx.x & 63;
    const int wv   = threadIdx.x >> 6;
    float* sw = pan[wv];

    const int nchunks = (B + 63) >> 6;
    const int W   = gridDim.x * WPB;       // total waves; 2 chunks each at B=1M
    const int wid = blockIdx.x * WPB + wv;

    float ent = 0.f, uniq = 0.f, corr = 0.f, rloo = 0.f;

    #pragma unroll 1   // keep ONE chunk's state live: no spills under 64-VGPR cap
    for (int ch = wid; ch < nchunks; ch += W) {
        const int base = ch << 6;
        const bool full = (base + 64) <= B;
        const bool inb  = full || (base + lane < B);

        // ---- samples first: consumed last, latency hides under the logs ----
        Samp sm;
        load_samp(sm, Y, s1g, s2g, B, base + lane, inb);

        // ---- stage 64 rows coalesced; fused log + entropy + panel write ----
        // per-k fusion keeps the live set ~1 float4, compiler hoists loads
        // only as far as the 64-VGPR budget allows.
        const float4* src = reinterpret_cast<const float4*>(pCS + (size_t)base * 20);
        float4* dst = reinterpret_cast<float4*>(sw);
        #pragma unroll
        for (int k = 0; k < 5; ++k) {
            const int g = lane + (k << 6);
            float4 v = make_float4(1.f, 1.f, 1.f, 1.f);   // log(1)=0 tail padding
            if (full || (base + g / 5) < B) v = src[g];
            float4 lg;
            lg.x = __logf(v.x); lg.y = __logf(v.y);
            lg.z = __logf(v.z); lg.w = __logf(v.w);
            ent += v.x * lg.x + v.y * lg.y + v.z * lg.z + v.w * lg.w;
            dst[g] = lg;                                   // ds_write_b128
        }
        __builtin_amdgcn_wave_barrier();   // same-wave LDS w->r ordered by lgkmcnt

        if (inb) {
            int pr[S_CONST]; float c[S_CONST];
            float csum = 0.f;
            #pragma unroll
            for (int s = 0; s < S_CONST; ++s) {
                pr[s] = sm.a1[s] * 10 + sm.a2[s];
                c[s]  = (sm.a1[s] + sm.a2[s] == sm.y) ? 1.f : 0.f;
                csum += c[s];
            }
            corr += csum;

            #pragma unroll
            for (int i = 0; i < S_CONST; ++i) {
                bool dup = false;
                #pragma unroll
                for (int j = 0; j < i; ++j) dup = dup || (pr[i] == pr[j]);
                uniq += dup ? 0.f : 1.f;
            }

            const float* my = &sw[lane * 20];
            const float cs7 = csum * (1.0f / 7.0f);
            #pragma unroll
            for (int s = 0; s < S_CONST; ++s) {
                const float lp = my[sm.a1[s]] + my[10 + sm.a2[s]];  // log gathers
                const float adv = c[s] * (8.0f / 7.0f) - cs7;       // c-(csum-c)/7
                rloo += lp * adv;
            }
        }
        __builtin_amdgcn_wave_barrier();   // next iter's writes stay behind reads
    }

    // ---- 64-lane butterfly ----
    #pragma unroll
    for (int off = 32; off >= 1; off >>= 1) {
        ent  += __shfl_xor(ent,  off);
        uniq += __shfl_xor(uniq, off);
        corr += __shfl_xor(corr, off);
        rloo += __shfl_xor(rloo, off);
    }

    // ---- cross-wave reduce reusing (dead) pan[0] as scratch ----
    __syncthreads();
    if (lane == 0) {
        float* r = pan[0];
        r[wv * 4 + 0] = ent;  r[wv * 4 + 1] = uniq;
        r[wv * 4 + 2] = corr; r[wv * 4 + 3] = rloo;
    }
    __syncthreads();
    if (threadIdx.x == 0) {
        const float* r = pan[0];
        float4 p;
        p.x = r[0] + r[4] + r[8]  + r[12];
        p.y = r[1] + r[5] + r[9]  + r[13];
        p.z = r[2] + r[6] + r[10] + r[14];
        p.w = r[3] + r[7] + r[11] + r[15];
        partials[blockIdx.x] = p;
    }
}

__global__ __launch_bounds__(1024) void fml_finalize(
        const float4* __restrict__ partials,
        const float* __restrict__ base_loss,
        float* __restrict__ out, int B, int nblocks)
{
    __shared__ double red[16][4];
    double e = 0, u = 0, cs = 0, rl = 0;
    for (int i = threadIdx.x; i < nblocks; i += 1024) {
        const float4 p = partials[i];
        e += (double)p.x; u += (double)p.y; cs += (double)p.z; rl += (double)p.w;
    }
    #pragma unroll
    for (int off = 32; off >= 1; off >>= 1) {
        e  += __shfl_xor(e,  off);
        u  += __shfl_xor(u,  off);
        cs += __shfl_xor(cs, off);
        rl += __shfl_xor(rl, off);
    }
    const int lane = threadIdx.x & 63;
    const int wave = threadIdx.x >> 6;
    if (lane == 0) { red[wave][0] = e; red[wave][1] = u; red[wave][2] = cs; red[wave][3] = rl; }
    __syncthreads();
    if (threadIdx.x == 0) {
        e = 0; u = 0; cs = 0; rl = 0;
        #pragma unroll
        for (int w = 0; w < 16; ++w) {
            e += red[w][0]; u += red[w][1]; cs += red[w][2]; rl += red[w][3];
        }
        const double dB = (double)B;
        const float entropy_loss = (float)(e / (2.0 * dB));   // = -(ent1+ent2)/2
        const float diversity = (float)(u / dB);
        const float ratio = diversity / 8.0f;                 // max_diversity = 8
        const float diversity_loss = -logf(ratio + EPSF);
        const float sample_acc = (float)(cs / (dB * (double)S_CONST));
        const float rloo_loss  = (float)(-rl / (dB * (double)S_CONST));
        out[0] = base_loss[0] + 0.01f * entropy_loss + 0.1f * diversity_loss;
        out[1] = rloo_loss;
        out[2] = diversity_loss;
        out[3] = sample_acc;
    }
}

extern "C" void kernel_launch(void* const* d_in, const int* in_sizes, int n_in,
                              void* d_out, int out_size, void* d_ws, size_t ws_size,
                              hipStream_t stream) {
    const float* pCS       = (const float*)d_in[0];
    const float* base_loss = (const float*)d_in[1];
    const int*   Y         = (const int*)d_in[2];
    const int*   s1        = (const int*)d_in[3];
    const int*   s2        = (const int*)d_in[4];
    float* out = (float*)d_out;
    const int B = in_sizes[2];

    const int nchunks = (B + 63) >> 6;
    const int waves   = (nchunks + 1) >> 1;          // 2 chunks per wave
    const int blocks  = (waves + WPB - 1) / WPB;     // 2048 at B=1M -> 8 blocks/CU

    float4* partials = (float4*)d_ws;                // 2048 * 16 B = 32 KB

    fml_reduce<<<blocks, 256, 0, stream>>>(pCS, Y, s1, s2, partials, B);
    fml_finalize<<<1, 1024, 0, stream>>>(partials, base_loss, out, B, blocks);
}

// Round 11
// 35.831 us; speedup vs baseline: 2.4395x; 2.4395x over previous
//
#include <hip/hip_runtime.h>

#define S_CONST 8
#define EPSF 1e-8f
#define WPB 4

struct Samp { int y; int a1[S_CONST]; int a2[S_CONST]; };

__device__ __forceinline__ void load_samp(Samp& sm, const int* __restrict__ Y,
                                          const int* __restrict__ s1g,
                                          const int* __restrict__ s2g,
                                          int B, int row, bool inb) {
    if (inb) {
        sm.y = Y[row];
        #pragma unroll
        for (int s = 0; s < S_CONST; ++s) {
            sm.a1[s] = s1g[(size_t)s * B + row];
            sm.a2[s] = s2g[(size_t)s * B + row];
        }
    } else {
        sm.y = -1;
        #pragma unroll
        for (int s = 0; s < S_CONST; ++s) { sm.a1[s] = 0; sm.a2[s] = 0; }
    }
}

// partials[nblocks]: float4 {ent, uniq, corr, rloo}
// NOTE: no min-waves bound — (256,8) forced the allocator into spilling
// (r9: 118MB fetch / r10: 184MB write of scratch). At natural ~44-56 VGPR
// (<=64) the HW grants 8 waves/SIMD by itself; LDS=20480 grants 8 blocks/CU.
__global__ __launch_bounds__(256) void fml_reduce(
        const float* __restrict__ pCS,
        const int* __restrict__ Y,
        const int* __restrict__ s1g,
        const int* __restrict__ s2g,
        float4* __restrict__ partials,
        int B)
{
    // EXACTLY 20480 B -> 8 blocks/CU; final reduce reuses pan[0] (validated r9/r10).
    __shared__ float pan[WPB][64 * 20];

    const int lane = threadIdx.x & 63;
    const int wv   = threadIdx.x >> 6;
    float* sw = pan[wv];

    const int nchunks = (B + 63) >> 6;
    const int W   = gridDim.x * WPB;       // total waves; 2 chunks each at B=1M
    const int wid = blockIdx.x * WPB + wv;

    float ent = 0.f, uniq = 0.f, corr = 0.f, rloo = 0.f;

    #pragma unroll 1   // one chunk's state live at a time
    for (int ch = wid; ch < nchunks; ch += W) {
        const int base = ch << 6;
        const bool full = (base + 64) <= B;
        const bool inb  = full || (base + lane < B);

        // ---- samples first: consumed last, latency hides under the logs ----
        Samp sm;
        load_samp(sm, Y, s1g, s2g, B, base + lane, inb);

        // ---- stage 64 rows coalesced; fused log + entropy + panel write ----
        const float4* src = reinterpret_cast<const float4*>(pCS + (size_t)base * 20);
        float4* dst = reinterpret_cast<float4*>(sw);
        #pragma unroll
        for (int k = 0; k < 5; ++k) {
            const int g = lane + (k << 6);
            float4 v = make_float4(1.f, 1.f, 1.f, 1.f);   // log(1)=0 tail padding
            if (full || (base + g / 5) < B) v = src[g];
            float4 lg;
            lg.x = __logf(v.x); lg.y = __logf(v.y);
            lg.z = __logf(v.z); lg.w = __logf(v.w);
            ent += v.x * lg.x + v.y * lg.y + v.z * lg.z + v.w * lg.w;
            dst[g] = lg;                                   // ds_write_b128
        }
        __builtin_amdgcn_wave_barrier();   // same-wave LDS w->r ordered by lgkmcnt

        if (inb) {
            int pr[S_CONST]; float c[S_CONST];
            float csum = 0.f;
            #pragma unroll
            for (int s = 0; s < S_CONST; ++s) {
                pr[s] = sm.a1[s] * 10 + sm.a2[s];
                c[s]  = (sm.a1[s] + sm.a2[s] == sm.y) ? 1.f : 0.f;
                csum += c[s];
            }
            corr += csum;

            #pragma unroll
            for (int i = 0; i < S_CONST; ++i) {
                bool dup = false;
                #pragma unroll
                for (int j = 0; j < i; ++j) dup = dup || (pr[i] == pr[j]);
                uniq += dup ? 0.f : 1.f;
            }

            const float* my = &sw[lane * 20];
            const float cs7 = csum * (1.0f / 7.0f);
            #pragma unroll
            for (int s = 0; s < S_CONST; ++s) {
                const float lp = my[sm.a1[s]] + my[10 + sm.a2[s]];  // log gathers
                const float adv = c[s] * (8.0f / 7.0f) - cs7;       // c-(csum-c)/7
                rloo += lp * adv;
            }
        }
        __builtin_amdgcn_wave_barrier();   // next iter's writes stay behind reads
    }

    // ---- 64-lane butterfly ----
    #pragma unroll
    for (int off = 32; off >= 1; off >>= 1) {
        ent  += __shfl_xor(ent,  off);
        uniq += __shfl_xor(uniq, off);
        corr += __shfl_xor(corr, off);
        rloo += __shfl_xor(rloo, off);
    }

    // ---- cross-wave reduce reusing (dead) pan[0] as scratch ----
    __syncthreads();
    if (lane == 0) {
        float* r = pan[0];
        r[wv * 4 + 0] = ent;  r[wv * 4 + 1] = uniq;
        r[wv * 4 + 2] = corr; r[wv * 4 + 3] = rloo;
    }
    __syncthreads();
    if (threadIdx.x == 0) {
        const float* r = pan[0];
        float4 p;
        p.x = r[0] + r[4] + r[8]  + r[12];
        p.y = r[1] + r[5] + r[9]  + r[13];
        p.z = r[2] + r[6] + r[10] + r[14];
        p.w = r[3] + r[7] + r[11] + r[15];
        partials[blockIdx.x] = p;
    }
}

__global__ __launch_bounds__(1024) void fml_finalize(
        const float4* __restrict__ partials,
        const float* __restrict__ base_loss,
        float* __restrict__ out, int B, int nblocks)
{
    __shared__ double red[16][4];
    double e = 0, u = 0, cs = 0, rl = 0;
    for (int i = threadIdx.x; i < nblocks; i += 1024) {
        const float4 p = partials[i];
        e += (double)p.x; u += (double)p.y; cs += (double)p.z; rl += (double)p.w;
    }
    #pragma unroll
    for (int off = 32; off >= 1; off >>= 1) {
        e  += __shfl_xor(e,  off);
        u  += __shfl_xor(u,  off);
        cs += __shfl_xor(cs, off);
        rl += __shfl_xor(rl, off);
    }
    const int lane = threadIdx.x & 63;
    const int wave = threadIdx.x >> 6;
    if (lane == 0) { red[wave][0] = e; red[wave][1] = u; red[wave][2] = cs; red[wave][3] = rl; }
    __syncthreads();
    if (threadIdx.x == 0) {
        e = 0; u = 0; cs = 0; rl = 0;
        #pragma unroll
        for (int w = 0; w < 16; ++w) {
            e += red[w][0]; u += red[w][1]; cs += red[w][2]; rl += red[w][3];
        }
        const double dB = (double)B;
        const float entropy_loss = (float)(e / (2.0 * dB));   // = -(ent1+ent2)/2
        const float diversity = (float)(u / dB);
        const float ratio = diversity / 8.0f;                 // max_diversity = 8
        const float diversity_loss = -logf(ratio + EPSF);
        const float sample_acc = (float)(cs / (dB * (double)S_CONST));
        const float rloo_loss  = (float)(-rl / (dB * (double)S_CONST));
        out[0] = base_loss[0] + 0.01f * entropy_loss + 0.1f * diversity_loss;
        out[1] = rloo_loss;
        out[2] = diversity_loss;
        out[3] = sample_acc;
    }
}

extern "C" void kernel_launch(void* const* d_in, const int* in_sizes, int n_in,
                              void* d_out, int out_size, void* d_ws, size_t ws_size,
                              hipStream_t stream) {
    const float* pCS       = (const float*)d_in[0];
    const float* base_loss = (const float*)d_in[1];
    const int*   Y         = (const int*)d_in[2];
    const int*   s1        = (const int*)d_in[3];
    const int*   s2        = (const int*)d_in[4];
    float* out = (float*)d_out;
    const int B = in_sizes[2];

    const int nchunks = (B + 63) >> 6;
    const int waves   = (nchunks + 1) >> 1;          // 2 chunks per wave
    const int blocks  = (waves + WPB - 1) / WPB;     // 2048 at B=1M -> 8 blocks/CU

    float4* partials = (float4*)d_ws;                // 2048 * 16 B = 32 KB

    fml_reduce<<<blocks, 256, 0, stream>>>(pCS, Y, s1, s2, partials, B);
    fml_finalize<<<1, 1024, 0, stream>>>(partials, base_loss, out, B, blocks);
}